// Round 10
// baseline (411.573 us; speedup 1.0000x reference)
//
#include <hip/hip_runtime.h>
#include <hip/hip_bf16.h>
#include <stdint.h>

#define N_TOKENS 8192
#define IN_F 4096
#define OUT_F 4096

#define BM 256
#define BN 256
#define BKB 64             // K-bytes per K-tile (one 16x16x64 k-slice)
#define NKT (IN_F / BKB)   // 64 K-tiles
#define NBUF 4             // 4-deep LDS ring -> 3 K-tiles prefetch distance

typedef int int32x4 __attribute__((ext_vector_type(4)));

__device__ __forceinline__ void gload_lds16(const signed char* g, signed char* lds) {
  __builtin_amdgcn_global_load_lds(
      (const __attribute__((address_space(1))) void*)g,
      (__attribute__((address_space(3))) void*)lds, 16, 0, 0);
}

// ---- pack: int32 -> int8, grid-stride; 16B coalesced reads, 4B writes ----
__global__ void pack_kernel(const int4* __restrict__ xs, const int4* __restrict__ ws,
                            uchar4* __restrict__ xd, uchar4* __restrict__ wd,
                            int n4x, int n4tot) {
  const int stride = gridDim.x * blockDim.x;
  for (int i = blockIdx.x * blockDim.x + threadIdx.x; i < n4tot; i += stride) {
    int4 v;
    if (i < n4x) v = xs[i];
    else v = ws[i - n4x];
    uchar4 p;
    p.x = (unsigned char)(v.x & 255);
    p.y = (unsigned char)(v.y & 255);
    p.z = (unsigned char)(v.z & 255);
    p.w = (unsigned char)(v.w & 255);
    if (i < n4x) xd[i] = p;
    else wd[i - n4x] = p;
  }
}

// ---- int8 MFMA GEMM, 256x256 tile, 8 waves, 4-ring deep-prefetch pipeline ----
// A: [N_TOKENS][IN_F] i8, B: [OUT_F][IN_F] i8; C = A @ B^T, requant epilogue.
// Per K-tile (64B): 2 phases x {ds_read cluster | 2 gload_lds | 16 MFMA}.
// While computing tile t, staging tile t+3; one counted vmcnt(8)/tile.
// 64B row stride tiles the 32 LDS banks exactly -> no swizzle needed.
__global__ __launch_bounds__(512, 2) void gemm_i8(
    const signed char* __restrict__ A, const signed char* __restrict__ B,
    const int* __restrict__ bias, const float* __restrict__ wscale,
    int* __restrict__ out) {
  __shared__ __align__(16) signed char sA[NBUF][BM * BKB];  // 4 x 16 KB
  __shared__ __align__(16) signed char sB[NBUF][BN * BKB];  // 4 x 16 KB

  const int tid = threadIdx.x;
  const int lane = tid & 63;
  const int w = tid >> 6;  // wave 0..7
  const int wr = w >> 2;   // 0..1 : M-panel (128 rows)
  const int wc = w & 3;    // 0..3 : N-panel (64 cols)

  const int brow = blockIdx.y * BM;
  const int bcol = blockIdx.x * BN;

  // staging: group = 128 rows x 64B = 8KB = 512 threads x 16B; 2 groups/tile.
  // row = tid>>2, chunk = tid&3; LDS dest linear in tid (gload_lds req).
  const int grow = tid >> 2;
  const signed char* gA = A + (size_t)(brow + grow) * IN_F + ((tid & 3) << 4);
  const signed char* gB = B + (size_t)(bcol + grow) * IN_F + ((tid & 3) << 4);
  const int lst = tid << 4;
#define GSTR ((size_t)128 * IN_F)  // group source stride (128 rows)

  // fragment reads: byte = (panel + m*16 + (lane&15))*64 + (lane>>4)*16
  const int rA = (wr * 128 + (lane & 15)) * BKB + ((lane >> 4) << 4);
  const int rB = (wc * 64 + (lane & 15)) * BKB + ((lane >> 4) << 4);

  int32x4 acc[8][4];
#pragma unroll
  for (int m = 0; m < 8; ++m)
#pragma unroll
    for (int n = 0; n < 4; ++n) acc[m][n] = (int32x4){0, 0, 0, 0};

  // prologue: stage tiles 0,1,2 into bufs 0,1,2 (12 loads, oldest first)
#pragma unroll
  for (int tt = 0; tt < 3; ++tt) {
    gload_lds16(gB + tt * BKB, &sB[tt][lst]);
    gload_lds16(gB + tt * BKB + GSTR, &sB[tt][8192 + lst]);
    gload_lds16(gA + tt * BKB, &sA[tt][lst]);
    gload_lds16(gA + tt * BKB + GSTR, &sA[tt][8192 + lst]);
  }
  asm volatile("s_waitcnt vmcnt(8)" ::: "memory");  // tile 0's 4 landed
  __builtin_amdgcn_s_barrier();

  for (int t = 0; t < NKT; ++t) {
    const int buf = t & (NBUF - 1);
    const int sbuf = (t + 3) & (NBUF - 1);
    const bool pf = (t < NKT - 3);
    const size_t so = (size_t)(t + 3) * BKB;
    int32x4 a[4], b[4];

    // ---- P0: m 0-3 x n 0-3 (8 ds_reads; stage B of t+3) ----
#pragma unroll
    for (int n = 0; n < 4; ++n) b[n] = *(const int32x4*)&sB[buf][rB + n * 1024];
#pragma unroll
    for (int m = 0; m < 4; ++m) a[m] = *(const int32x4*)&sA[buf][rA + m * 1024];
    if (pf) { gload_lds16(gB + so, &sB[sbuf][lst]); gload_lds16(gB + so + GSTR, &sB[sbuf][8192 + lst]); }
    __builtin_amdgcn_s_barrier();
    asm volatile("s_waitcnt lgkmcnt(0)" ::: "memory");
    __builtin_amdgcn_sched_barrier(0);
    __builtin_amdgcn_s_setprio(1);
#pragma unroll
    for (int m = 0; m < 4; ++m)
#pragma unroll
      for (int n = 0; n < 4; ++n)
        acc[m][n] = __builtin_amdgcn_mfma_i32_16x16x64_i8(a[m], b[n], acc[m][n], 0, 0, 0);
    __builtin_amdgcn_s_setprio(0);
    __builtin_amdgcn_s_barrier();

    // ---- P1: m 4-7 x n 0-3 (4 ds_reads; stage A of t+3) ----
#pragma unroll
    for (int m = 0; m < 4; ++m) a[m] = *(const int32x4*)&sA[buf][rA + (m + 4) * 1024];
    if (pf) { gload_lds16(gA + so, &sA[sbuf][lst]); gload_lds16(gA + so + GSTR, &sA[sbuf][8192 + lst]); }
    __builtin_amdgcn_s_barrier();
    asm volatile("s_waitcnt lgkmcnt(0)" ::: "memory");
    __builtin_amdgcn_sched_barrier(0);
    __builtin_amdgcn_s_setprio(1);
#pragma unroll
    for (int m = 0; m < 4; ++m)
#pragma unroll
      for (int n = 0; n < 4; ++n)
        acc[m + 4][n] = __builtin_amdgcn_mfma_i32_16x16x64_i8(a[m], b[n], acc[m + 4][n], 0, 0, 0);
    __builtin_amdgcn_s_setprio(0);

    // boundary: tile t+1's loads (issued 3 tiles ago) must have landed;
    // tiles t+2/t+3 (<=8 loads) stay in flight -- counted, never drain.
    if (t < NKT - 3) {
      asm volatile("s_waitcnt vmcnt(8)" ::: "memory");
      __builtin_amdgcn_s_barrier();
    } else if (t == NKT - 3) {
      asm volatile("s_waitcnt vmcnt(4)" ::: "memory");
      __builtin_amdgcn_s_barrier();
    } else if (t == NKT - 2) {
      asm volatile("s_waitcnt vmcnt(0)" ::: "memory");
      __builtin_amdgcn_s_barrier();
    }
  }
#undef GSTR

  // epilogue: C/D layout col=lane&15, row=(lane>>4)*4+reg. OUTPUT IS INT32.
  const int colb = bcol + wc * 64 + (lane & 15);
  const int rowb = brow + wr * 128 + ((lane >> 4) << 2);
#pragma unroll
  for (int n = 0; n < 4; ++n) {
    const int col = colb + n * 16;
    const float s = 0.02f * wscale[col] / 0.05f;
    const int bz = bias[col];
#pragma unroll
    for (int m = 0; m < 8; ++m) {
      const int row0 = rowb + m * 16;
#pragma unroll
      for (int r = 0; r < 4; ++r) {
        float f = (float)(acc[m][n][r] + bz) * s;
        f = rintf(f);                        // round-half-even == jnp.round
        f = fminf(127.f, fmaxf(-128.f, f));  // clip
        out[(size_t)(row0 + r) * OUT_F + col] = (int)f;
      }
    }
  }
}

extern "C" void kernel_launch(void* const* d_in, const int* in_sizes, int n_in,
                              void* d_out, int out_size, void* d_ws, size_t ws_size,
                              hipStream_t stream) {
  const int* x = (const int*)d_in[0];        // [8192,4096] values in [-128,127]
  const int* w = (const int*)d_in[1];        // [4096,4096]
  const int* bias = (const int*)d_in[2];     // [4096]
  const float* wsc = (const float*)d_in[3];  // [4096]
  int* out = (int*)d_out;

  signed char* xp = (signed char*)d_ws;            // 32 MB
  signed char* wp = xp + (size_t)N_TOKENS * IN_F;  // 16 MB

  const int n4x = N_TOKENS * IN_F / 4;
  const int n4w = OUT_F * IN_F / 4;
  const int n4tot = n4x + n4w;

  pack_kernel<<<2048, 256, 0, stream>>>((const int4*)x, (const int4*)w,
                                        (uchar4*)xp, (uchar4*)wp, n4x, n4tot);

  dim3 grid(OUT_F / BN, N_TOKENS / BM);  // (16, 32) = 512 blocks
  gemm_i8<<<grid, dim3(512), 0, stream>>>(xp, wp, bias, wsc, out);
}